// Round 7
// baseline (160.743 us; speedup 1.0000x reference)
//
#include <hip/hip_runtime.h>
#include <hip/hip_bf16.h>

// Problem constants
constexpr int BATCH = 4;
constexpr int NSEQ  = 1024;
constexpr int CDIM  = 768;
constexpr int NHEAD = 12;
constexpr int HDIM  = 64;
constexpr int MTOT  = BATCH * NSEQ;   // 4096
constexpr int QKVN  = 3 * CDIM;       // 2304

typedef __bf16 bf16x8 __attribute__((ext_vector_type(8)));
typedef float  f32x4  __attribute__((ext_vector_type(4)));

__device__ __forceinline__ unsigned short f2bf(float f) {
    unsigned u = __builtin_bit_cast(unsigned, f);
    unsigned r = u + 0x7FFFu + ((u >> 16) & 1u);   // RNE
    return (unsigned short)(r >> 16);
}

#define GLOAD_LDS16(gp, lp)                                                    \
    __builtin_amdgcn_global_load_lds(                                          \
        (const __attribute__((address_space(1))) void*)(gp),                   \
        (__attribute__((address_space(3))) void*)(lp), 16, 0, 0)

// ---------------------------------------------------------------------------
// Prologue converts
// ---------------------------------------------------------------------------
__global__ __launch_bounds__(256) void cvt_f32_bf16(
    const float* __restrict__ in, unsigned short* __restrict__ out, int n4)
{
    int i = blockIdx.x * 256 + threadIdx.x;
    if (i < n4) {
        float4 a = reinterpret_cast<const float4*>(in)[i];
        ushort4 h;
        h.x = f2bf(a.x); h.y = f2bf(a.y); h.z = f2bf(a.z); h.w = f2bf(a.w);
        reinterpret_cast<ushort4*>(out)[i] = h;
    }
}

// in [R][C] f32  ->  out [C][R] bf16  (32x32 tiles)
__global__ __launch_bounds__(256) void tcvt_f32_bf16(
    const float* __restrict__ in, unsigned short* __restrict__ out, int R, int C)
{
    __shared__ unsigned short t[32][33];
    const int c0 = blockIdx.x * 32, r0 = blockIdx.y * 32;
    const int tc = threadIdx.x & 31, tr = threadIdx.x >> 5;  // tr 0..7
    #pragma unroll
    for (int i = 0; i < 4; i++)
        t[tc][tr + 8 * i] = f2bf(in[(size_t)(r0 + tr + 8 * i) * C + c0 + tc]);
    __syncthreads();
    #pragma unroll
    for (int i = 0; i < 4; i++)
        out[(size_t)(c0 + tr + 8 * i) * R + r0 + tc] = t[tr + 8 * i][tc];
}

// ---------------------------------------------------------------------------
// QKV GEMM: xb [4096,768] bf16 @ wt [2304,768] bf16 (pre-transposed) + bias
// -> scatter bf16 into Q*0.125 [B,H,N,64], K [B,H,N,64], Vt [B,H,64,N]
// (scale folded into Q here: 0.125 is a power of two -> exact in bf16)
// ---------------------------------------------------------------------------
__global__ __launch_bounds__(256) void qkv_gemm(
    const unsigned short* __restrict__ xb,   // [4096][768]
    const unsigned short* __restrict__ wt,   // [2304][768]
    const float* __restrict__ bias,
    unsigned short* __restrict__ qbuf, unsigned short* __restrict__ kbuf,
    unsigned short* __restrict__ vtbuf)
{
    __shared__ unsigned short As[128 * 32];
    __shared__ unsigned short Bs[128 * 32];
    const int tid  = threadIdx.x;
    const int lane = tid & 63;
    const int wid  = tid >> 6;
    const int wm = (wid >> 1) * 64, wn = (wid & 1) * 64;
    const int g = lane >> 4, li = lane & 15;
    const int m0 = blockIdx.y * 128;
    const int n0 = blockIdx.x * 128;
    const int srow = lane >> 2;
    const int scol = (lane & 3) * 8;

    f32x4 acc[4][4];
    #pragma unroll
    for (int i = 0; i < 4; i++)
        #pragma unroll
        for (int j = 0; j < 4; j++) acc[i][j] = f32x4{0.f, 0.f, 0.f, 0.f};

    for (int k0 = 0; k0 < CDIM; k0 += 32) {
        __syncthreads();
        #pragma unroll
        for (int c = 0; c < 2; c++) {
            int row = wid * 32 + c * 16 + srow;
            GLOAD_LDS16(&xb[(size_t)(m0 + row) * CDIM + k0 + scol],
                        &As[(wid * 32 + c * 16) * 32]);
            GLOAD_LDS16(&wt[(size_t)(n0 + row) * CDIM + k0 + scol],
                        &Bs[(wid * 32 + c * 16) * 32]);
        }
        __syncthreads();
        bf16x8 a[4], b[4];
        #pragma unroll
        for (int mt = 0; mt < 4; mt++)
            a[mt] = *reinterpret_cast<const bf16x8*>(&As[(wm + 16 * mt + li) * 32 + 8 * g]);
        #pragma unroll
        for (int nt = 0; nt < 4; nt++)
            b[nt] = *reinterpret_cast<const bf16x8*>(&Bs[(wn + 16 * nt + li) * 32 + 8 * g]);
        #pragma unroll
        for (int mt = 0; mt < 4; mt++)
            #pragma unroll
            for (int nt = 0; nt < 4; nt++)
                acc[mt][nt] = __builtin_amdgcn_mfma_f32_16x16x32_bf16(a[mt], b[nt], acc[mt][nt], 0, 0, 0);
    }

    #pragma unroll
    for (int mt = 0; mt < 4; mt++) {
        #pragma unroll
        for (int nt = 0; nt < 4; nt++) {
            int col  = n0 + wn + 16 * nt + li;
            int tsel = col / CDIM;
            int rem  = col - tsel * CDIM;
            int h_ = rem >> 6, d = rem & 63;
            float bv = bias[col];
            float sc = (tsel == 0) ? 0.125f : 1.0f;
            #pragma unroll
            for (int r = 0; r < 4; r++) {
                int m  = m0 + wm + 16 * mt + 4 * g + r;
                int b_ = m >> 10, s = m & 1023;
                unsigned short hv = f2bf((acc[mt][nt][r] + bv) * sc);
                if (tsel == 0)
                    qbuf[(((size_t)b_ * NHEAD + h_) * NSEQ + s) * HDIM + d] = hv;
                else if (tsel == 1)
                    kbuf[(((size_t)b_ * NHEAD + h_) * NSEQ + s) * HDIM + d] = hv;
                else
                    vtbuf[(((size_t)b_ * NHEAD + h_) * HDIM + d) * NSEQ + s] = hv;
            }
        }
    }
}

// ---------------------------------------------------------------------------
// Flash-style attention, no-max softmax, 2-phase async pipeline:
// K/V double-buffered in linear LDS via global_load_lds (tile t+1 staged
// before tile t's compute), XOR-swizzled via pre-swizzled global source
// (rule #21), bias prefetched per tile into named register sets (no
// loop-parity arrays -> no scratch). KVBLK=64, 16 tiles, 2 tiles/iter.
// ---------------------------------------------------------------------------
__global__ __launch_bounds__(256, 3) void attn_kernel(
    const unsigned short* __restrict__ qbuf,
    const unsigned short* __restrict__ kbuf,
    const unsigned short* __restrict__ vtbuf,
    const float* __restrict__ bias,     // [H,N,N]
    unsigned short* __restrict__ ybuf)  // [B,N,C] bf16
{
    __shared__ unsigned short Kl[2][64 * 64];  // linear [k][d], source-swizzled
    __shared__ unsigned short Vl[2][64 * 64];  // linear [d][k], source-swizzled
    __shared__ unsigned short Ps[4][16][72];   // per-wave P^T: [q][k], padded

    const int tid  = threadIdx.x;
    const int lane = tid & 63;
    const int wid  = tid >> 6;
    const int g = lane >> 4, li = lane & 15;
    const int srow8 = lane >> 3;                  // 0..7
    const int scs   = (lane & 7) ^ srow8;         // swizzled source slot

    // XCD-chunked swizzle (bijective, 768%8==0): per chunk 4 batches share
    // bias rows (L2), 16 q-tiles of each (b,h) on one XCD (K/V L2-resident).
    const int lin = blockIdx.x;
    const int s   = (lin & 7) * 96 + (lin >> 3);
    const int b_    = s & 3;
    const int hq    = s >> 2;
    const int qtile = hq & 15;
    const int h_    = hq >> 4;
    const int bh    = b_ * NHEAD + h_;
    const int qw = qtile * 64 + wid * 16;

    const unsigned short* qb = qbuf + (size_t)bh * NSEQ * HDIM;
    const unsigned short* kb = kbuf + (size_t)bh * NSEQ * HDIM;
    const unsigned short* vb = vtbuf + (size_t)bh * HDIM * NSEQ;
    const float* bb = bias + (size_t)h_ * NSEQ * NSEQ;

    // stage tile T into buffer: 2 K + 2 V global_load_lds per wave.
    // source column slot XOR'd with row&7 so linear LDS holds swizzled data.
#define STAGE_KV(T, KLDST, VLDST)                                              \
    {                                                                          \
        _Pragma("unroll") for (int i = 0; i < 2; i++) {                        \
            GLOAD_LDS16(kb + ((size_t)((T) * 64 + wid * 16 + i * 8 + srow8)) * HDIM + scs * 8, \
                        (KLDST) + (wid * 16 + i * 8) * 64);                    \
            GLOAD_LDS16(vb + (size_t)(wid * 16 + i * 8 + srow8) * NSEQ + (T) * 64 + scs * 8,   \
                        (VLDST) + (wid * 16 + i * 8) * 64);                    \
        }                                                                      \
    }

#define LOAD_BIAS(BV, T)                                                       \
    {                                                                          \
        _Pragma("unroll") for (int kt = 0; kt < 4; kt++)                       \
            (BV)[kt] = *reinterpret_cast<const f32x4*>(                        \
                &bb[(size_t)(qw + li) * NSEQ + (T) * 64 + 16 * kt + 4 * g]);   \
    }

    // compute one 64-key tile from (KP,VP) with bias BV
#define COMPUTE_TILE(KP, VP, BV)                                               \
    {                                                                          \
        f32x4 sacc[4];                                                         \
        _Pragma("unroll") for (int kt = 0; kt < 4; kt++)                       \
            sacc[kt] = f32x4{0.f, 0.f, 0.f, 0.f};                              \
        _Pragma("unroll") for (int kt = 0; kt < 4; kt++)                       \
            _Pragma("unroll") for (int dd = 0; dd < 2; dd++) {                 \
                bf16x8 kf = *reinterpret_cast<const bf16x8*>(                  \
                    (KP) + (16 * kt + li) * 64 + (((4 * dd + g) ^ (li & 7)) * 8)); \
                sacc[kt] = __builtin_amdgcn_mfma_f32_16x16x32_bf16(kf, qf[dd], sacc[kt], 0, 0, 0); \
            }                                                                  \
        _Pragma("unroll") for (int kt = 0; kt < 4; kt++) {                     \
            ushort4 pk;                                                        \
            float p0 = __expf(sacc[kt][0] + (BV)[kt][0]);                      \
            float p1 = __expf(sacc[kt][1] + (BV)[kt][1]);                      \
            float p2 = __expf(sacc[kt][2] + (BV)[kt][2]);                      \
            float p3 = __expf(sacc[kt][3] + (BV)[kt][3]);                      \
            lpart += p0 + p1 + p2 + p3;                                        \
            pk.x = f2bf(p0); pk.y = f2bf(p1); pk.z = f2bf(p2); pk.w = f2bf(p3);\
            *reinterpret_cast<ushort4*>(&Ps[wid][li][16 * kt + 4 * g]) = pk;   \
        }                                                                      \
        _Pragma("unroll") for (int kk = 0; kk < 2; kk++) {                     \
            bf16x8 pf = *reinterpret_cast<const bf16x8*>(&Ps[wid][li][32 * kk + 8 * g]); \
            _Pragma("unroll") for (int dt = 0; dt < 4; dt++) {                 \
                bf16x8 vf = *reinterpret_cast<const bf16x8*>(                  \
                    (VP) + (16 * dt + li) * 64 + (((4 * kk + g) ^ (li & 7)) * 8)); \
                oacc[dt] = __builtin_amdgcn_mfma_f32_16x16x32_bf16(pf, vf, oacc[dt], 0, 0, 0); \
            }                                                                  \
        }                                                                      \
    }

    bf16x8 qf[2];
    #pragma unroll
    for (int dd = 0; dd < 2; dd++)
        qf[dd] = *reinterpret_cast<const bf16x8*>(&qb[(size_t)(qw + li) * HDIM + 32 * dd + 8 * g]);

    f32x4 oacc[4];
    #pragma unroll
    for (int dt = 0; dt < 4; dt++) oacc[dt] = f32x4{0.f, 0.f, 0.f, 0.f};
    float lpart = 0.f;

    f32x4 bvA[4], bvB[4];

    // prologue: stage tile 0, bias 0
    STAGE_KV(0, Kl[0], Vl[0]);
    LOAD_BIAS(bvA, 0);
    __syncthreads();   // drains DMA for tile 0

    #pragma unroll
    for (int j = 0; j < 8; ++j) {
        const int tA = 2 * j;
        // phase 1: prefetch tile tA+1 under tile tA's compute
        STAGE_KV(tA + 1, Kl[1], Vl[1]);
        LOAD_BIAS(bvB, tA + 1);
        COMPUTE_TILE(Kl[0], Vl[0], bvA);
        __syncthreads();   // all waves done with buf0; tile tA+1 DMA drained

        // phase 2: prefetch tile tA+2 under tile tA+1's compute
        if (j < 7) {
            STAGE_KV(tA + 2, Kl[0], Vl[0]);
            LOAD_BIAS(bvA, tA + 2);
        }
        COMPUTE_TILE(Kl[1], Vl[1], bvB);
        __syncthreads();   // all waves done with buf1; tile tA+2 DMA drained
    }

    // l-reduce: lane (g,li) holds partial for q=li; sum over g, gather.
    lpart += __shfl_xor(lpart, 16);
    lpart += __shfl_xor(lpart, 32);
    float linv[4];
    #pragma unroll
    for (int r = 0; r < 4; r++)
        linv[r] = 1.f / __shfl(lpart, 4 * g + r);

    #pragma unroll
    for (int dt = 0; dt < 4; dt++)
        #pragma unroll
        for (int r = 0; r < 4; r++) {
            float o = oacc[dt][r] * linv[r];
            int sq = qw + 4 * g + r;
            ybuf[((size_t)b_ * NSEQ + sq) * CDIM + h_ * HDIM + 16 * dt + li] = f2bf(o);
        }
#undef STAGE_KV
#undef LOAD_BIAS
#undef COMPUTE_TILE
}

// ---------------------------------------------------------------------------
// Proj GEMM: ybuf [4096,768] bf16 @ pwt [768,768] bf16 (pre-transposed)
// + proj_b -> fp32 out.
// ---------------------------------------------------------------------------
__global__ __launch_bounds__(256) void proj_gemm(
    const unsigned short* __restrict__ yb,   // [4096][768]
    const unsigned short* __restrict__ pwt,  // [768][768] (n,k)
    const float* __restrict__ bias, float* __restrict__ out)
{
    __shared__ unsigned short As[128 * 32];
    __shared__ unsigned short Bs[128 * 32];
    const int tid  = threadIdx.x;
    const int lane = tid & 63;
    const int wid  = tid >> 6;
    const int wm = (wid >> 1) * 64, wn = (wid & 1) * 64;
    const int g = lane >> 4, li = lane & 15;
    const int m0 = blockIdx.y * 128;
    const int n0 = blockIdx.x * 128;
    const int srow = lane >> 2;
    const int scol = (lane & 3) * 8;

    f32x4 acc[4][4];
    #pragma unroll
    for (int i = 0; i < 4; i++)
        #pragma unroll
        for (int j = 0; j < 4; j++) acc[i][j] = f32x4{0.f, 0.f, 0.f, 0.f};

    for (int k0 = 0; k0 < CDIM; k0 += 32) {
        __syncthreads();
        #pragma unroll
        for (int c = 0; c < 2; c++) {
            int row = wid * 32 + c * 16 + srow;
            GLOAD_LDS16(&yb[(size_t)(m0 + row) * CDIM + k0 + scol],
                        &As[(wid * 32 + c * 16) * 32]);
            GLOAD_LDS16(&pwt[(size_t)(n0 + row) * CDIM + k0 + scol],
                        &Bs[(wid * 32 + c * 16) * 32]);
        }
        __syncthreads();
        bf16x8 a[4], b[4];
        #pragma unroll
        for (int mt = 0; mt < 4; mt++)
            a[mt] = *reinterpret_cast<const bf16x8*>(&As[(wm + 16 * mt + li) * 32 + 8 * g]);
        #pragma unroll
        for (int nt = 0; nt < 4; nt++)
            b[nt] = *reinterpret_cast<const bf16x8*>(&Bs[(wn + 16 * nt + li) * 32 + 8 * g]);
        #pragma unroll
        for (int mt = 0; mt < 4; mt++)
            #pragma unroll
            for (int nt = 0; nt < 4; nt++)
                acc[mt][nt] = __builtin_amdgcn_mfma_f32_16x16x32_bf16(a[mt], b[nt], acc[mt][nt], 0, 0, 0);
    }

    #pragma unroll
    for (int mt = 0; mt < 4; mt++)
        #pragma unroll
        for (int nt = 0; nt < 4; nt++) {
            int col = n0 + wn + 16 * nt + li;
            float bv = bias[col];
            #pragma unroll
            for (int r = 0; r < 4; r++) {
                int m = m0 + wm + 16 * mt + 4 * g + r;
                out[(size_t)m * CDIM + col] = acc[mt][nt][r] + bv;
            }
        }
}

extern "C" void kernel_launch(void* const* d_in, const int* in_sizes, int n_in,
                              void* d_out, int out_size, void* d_ws, size_t ws_size,
                              hipStream_t stream) {
    const float* x         = (const float*)d_in[0];
    const float* attn_bias = (const float*)d_in[1];
    const float* qkv_w     = (const float*)d_in[2];
    const float* qkv_b     = (const float*)d_in[3];
    const float* proj_w    = (const float*)d_in[4];
    const float* proj_b    = (const float*)d_in[5];
    float* out = (float*)d_out;

    const size_t per = (size_t)BATCH * NHEAD * NSEQ * HDIM;  // 3,145,728
    unsigned short* qbuf  = (unsigned short*)d_ws;
    unsigned short* kbuf  = qbuf + per;
    unsigned short* vtbuf = kbuf + per;
    unsigned short* xb    = vtbuf + per;
    unsigned short* qwt   = xb + per;                    // [2304][768]
    unsigned short* pwt   = qwt + (size_t)QKVN * CDIM;   // [768][768]
    unsigned short* ybuf  = xb;  // x dead after qkv_gemm

    cvt_f32_bf16<<<(MTOT * CDIM / 4 + 255) / 256, 256, 0, stream>>>(
        x, xb, MTOT * CDIM / 4);
    tcvt_f32_bf16<<<dim3(QKVN / 32, CDIM / 32), 256, 0, stream>>>(
        qkv_w, qwt, CDIM, QKVN);
    tcvt_f32_bf16<<<dim3(CDIM / 32, CDIM / 32), 256, 0, stream>>>(
        proj_w, pwt, CDIM, CDIM);

    qkv_gemm<<<dim3(QKVN / 128, MTOT / 128), 256, 0, stream>>>(
        xb, qwt, qkv_b, qbuf, kbuf, vtbuf);
    attn_kernel<<<768, 256, 0, stream>>>(
        qbuf, kbuf, vtbuf, attn_bias, ybuf);
    proj_gemm<<<dim3(CDIM / 128, MTOT / 128), 256, 0, stream>>>(
        ybuf, pwt, proj_b, out);
}

// Round 9
// 129.657 us; speedup vs baseline: 1.2398x; 1.2398x over previous
//
#include <hip/hip_runtime.h>
#include <hip/hip_bf16.h>

// Problem constants
constexpr int BATCH = 4;
constexpr int NSEQ  = 1024;
constexpr int CDIM  = 768;
constexpr int NHEAD = 12;
constexpr int HDIM  = 64;
constexpr int MTOT  = BATCH * NSEQ;   // 4096
constexpr int QKVN  = 3 * CDIM;       // 2304

typedef __bf16 bf16x8 __attribute__((ext_vector_type(8)));
typedef float  f32x4  __attribute__((ext_vector_type(4)));

__device__ __forceinline__ unsigned short f2bf(float f) {
    unsigned u = __builtin_bit_cast(unsigned, f);
    unsigned r = u + 0x7FFFu + ((u >> 16) & 1u);   // RNE
    return (unsigned short)(r >> 16);
}

// pack two f32 -> two bf16 in one dword (lo in low half) — pure VALU,
// replaces round-8's v_cvt_pk_bf16_f32 asm (produced NaN bit patterns).
__device__ __forceinline__ unsigned pack_bf16(float lo, float hi) {
    return (unsigned)f2bf(lo) | ((unsigned)f2bf(hi) << 16);
}

#define GLOAD_LDS16(gp, lp)                                                    \
    __builtin_amdgcn_global_load_lds(                                          \
        (const __attribute__((address_space(1))) void*)(gp),                   \
        (__attribute__((address_space(3))) void*)(lp), 16, 0, 0)

// ---------------------------------------------------------------------------
// Prologue converts
// ---------------------------------------------------------------------------
__global__ __launch_bounds__(256) void cvt_f32_bf16(
    const float* __restrict__ in, unsigned short* __restrict__ out, int n4)
{
    int i = blockIdx.x * 256 + threadIdx.x;
    if (i < n4) {
        float4 a = reinterpret_cast<const float4*>(in)[i];
        ushort4 h;
        h.x = f2bf(a.x); h.y = f2bf(a.y); h.z = f2bf(a.z); h.w = f2bf(a.w);
        reinterpret_cast<ushort4*>(out)[i] = h;
    }
}

// in [R][C] f32  ->  out [C][R] bf16  (32x32 tiles)
__global__ __launch_bounds__(256) void tcvt_f32_bf16(
    const float* __restrict__ in, unsigned short* __restrict__ out, int R, int C)
{
    __shared__ unsigned short t[32][33];
    const int c0 = blockIdx.x * 32, r0 = blockIdx.y * 32;
    const int tc = threadIdx.x & 31, tr = threadIdx.x >> 5;  // tr 0..7
    #pragma unroll
    for (int i = 0; i < 4; i++)
        t[tc][tr + 8 * i] = f2bf(in[(size_t)(r0 + tr + 8 * i) * C + c0 + tc]);
    __syncthreads();
    #pragma unroll
    for (int i = 0; i < 4; i++)
        out[(size_t)(c0 + tr + 8 * i) * R + r0 + tc] = t[tr + 8 * i][tc];
}

// ---------------------------------------------------------------------------
// QKV GEMM: xb [4096,768] bf16 @ wt [2304,768] bf16 (pre-transposed) + bias
// -> scatter bf16 into Q*0.125 [B,H,N,64], K [B,H,N,64], Vt [B,H,64,N]
// ---------------------------------------------------------------------------
__global__ __launch_bounds__(256) void qkv_gemm(
    const unsigned short* __restrict__ xb,   // [4096][768]
    const unsigned short* __restrict__ wt,   // [2304][768]
    const float* __restrict__ bias,
    unsigned short* __restrict__ qbuf, unsigned short* __restrict__ kbuf,
    unsigned short* __restrict__ vtbuf)
{
    __shared__ unsigned short As[128 * 32];
    __shared__ unsigned short Bs[128 * 32];
    const int tid  = threadIdx.x;
    const int lane = tid & 63;
    const int wid  = tid >> 6;
    const int wm = (wid >> 1) * 64, wn = (wid & 1) * 64;
    const int g = lane >> 4, li = lane & 15;
    const int m0 = blockIdx.y * 128;
    const int n0 = blockIdx.x * 128;
    const int srow = lane >> 2;
    const int scol = (lane & 3) * 8;

    f32x4 acc[4][4];
    #pragma unroll
    for (int i = 0; i < 4; i++)
        #pragma unroll
        for (int j = 0; j < 4; j++) acc[i][j] = f32x4{0.f, 0.f, 0.f, 0.f};

    for (int k0 = 0; k0 < CDIM; k0 += 32) {
        __syncthreads();
        #pragma unroll
        for (int c = 0; c < 2; c++) {
            int row = wid * 32 + c * 16 + srow;
            GLOAD_LDS16(&xb[(size_t)(m0 + row) * CDIM + k0 + scol],
                        &As[(wid * 32 + c * 16) * 32]);
            GLOAD_LDS16(&wt[(size_t)(n0 + row) * CDIM + k0 + scol],
                        &Bs[(wid * 32 + c * 16) * 32]);
        }
        __syncthreads();
        bf16x8 a[4], b[4];
        #pragma unroll
        for (int mt = 0; mt < 4; mt++)
            a[mt] = *reinterpret_cast<const bf16x8*>(&As[(wm + 16 * mt + li) * 32 + 8 * g]);
        #pragma unroll
        for (int nt = 0; nt < 4; nt++)
            b[nt] = *reinterpret_cast<const bf16x8*>(&Bs[(wn + 16 * nt + li) * 32 + 8 * g]);
        #pragma unroll
        for (int mt = 0; mt < 4; mt++)
            #pragma unroll
            for (int nt = 0; nt < 4; nt++)
                acc[mt][nt] = __builtin_amdgcn_mfma_f32_16x16x32_bf16(a[mt], b[nt], acc[mt][nt], 0, 0, 0);
    }

    #pragma unroll
    for (int mt = 0; mt < 4; mt++) {
        #pragma unroll
        for (int nt = 0; nt < 4; nt++) {
            int col  = n0 + wn + 16 * nt + li;
            int tsel = col / CDIM;
            int rem  = col - tsel * CDIM;
            int h_ = rem >> 6, d = rem & 63;
            float bv = bias[col];
            float sc = (tsel == 0) ? 0.125f : 1.0f;
            #pragma unroll
            for (int r = 0; r < 4; r++) {
                int m  = m0 + wm + 16 * mt + 4 * g + r;
                int b_ = m >> 10, s = m & 1023;
                unsigned short hv = f2bf((acc[mt][nt][r] + bv) * sc);
                if (tsel == 0)
                    qbuf[(((size_t)b_ * NHEAD + h_) * NSEQ + s) * HDIM + d] = hv;
                else if (tsel == 1)
                    kbuf[(((size_t)b_ * NHEAD + h_) * NSEQ + s) * HDIM + d] = hv;
                else
                    vtbuf[(((size_t)b_ * NHEAD + h_) * HDIM + d) * NSEQ + s] = hv;
            }
        }
    }
}

// ---------------------------------------------------------------------------
// Flash-style attention, no-max softmax (|logit| <= ~8 for this problem).
// Swapped QK^T + K-row permutation in LDS (position p holds K row sigma(p),
// sigma: within-slab 8*gp+4*h+r for p=16h+4gp+r) so each lane's S^T outputs
// are exactly its PV A-fragment k-slots (k = 32kk+8g+j, q = li).
// P packed lane-locally (pure-VALU bf16 pack); NO P LDS round-trip.
// LDS 35.8KB -> 4 blocks/CU. Serial stage (r3 structure; cross-barrier
// register prefetch spilled in r4/r5/r7).
// ---------------------------------------------------------------------------
__global__ __launch_bounds__(256, 4) void attn_kernel(
    const unsigned short* __restrict__ qbuf,
    const unsigned short* __restrict__ kbuf,
    const unsigned short* __restrict__ vtbuf,
    const float* __restrict__ bias,     // [H,N,N]
    unsigned short* __restrict__ ybuf)  // [B,N,C] bf16
{
    __shared__ unsigned short Ks[128 * 72];   // [pos][d], rows permuted
    __shared__ unsigned short Vs[64 * 136];   // V^T [d][k]

    const int tid  = threadIdx.x;
    const int lane = tid & 63;
    const int wid  = tid >> 6;
    const int g = lane >> 4, li = lane & 15;
    const int bh = blockIdx.y;
    const int b_ = bh / NHEAD, h_ = bh % NHEAD;
    const int qw = blockIdx.x * 64 + wid * 16;

    const unsigned short* qb = qbuf + (size_t)bh * NSEQ * HDIM;
    const unsigned short* kb = kbuf + (size_t)bh * NSEQ * HDIM;
    const unsigned short* vb = vtbuf + (size_t)bh * HDIM * NSEQ;
    const float* bb = bias + (size_t)h_ * NSEQ * NSEQ;

    // staging addresses (constant per thread): K row kr -> LDS position
    // pi(kr): keep bits 6,5,1,0; bit2->bit4; bits4,3->bits3,2.
    int ksrc[4], ksoff[4], vsrc[4], vsoff[4];
    #pragma unroll
    for (int i = 0; i < 4; i++) {
        int j = tid * 4 + i;
        int kr = j >> 3, kc = (j & 7) * 8;
        int kp = (kr & 0x63) | ((kr & 4) << 2) | ((kr & 0x18) >> 1);
        ksrc[i] = kr * HDIM + kc;
        ksoff[i] = kp * 72 + kc;
        int vr = j >> 4, vc = (j & 15) * 8;
        vsrc[i] = vr * NSEQ + vc;
        vsoff[i] = vr * 136 + vc;
    }

    bf16x8 qf[2];
    #pragma unroll
    for (int dd = 0; dd < 2; dd++)
        qf[dd] = *reinterpret_cast<const bf16x8*>(&qb[(size_t)(qw + li) * HDIM + 32 * dd + 8 * g]);

    f32x4 oacc[4];
    #pragma unroll
    for (int dt = 0; dt < 4; dt++) oacc[dt] = f32x4{0.f, 0.f, 0.f, 0.f};
    float lpart = 0.f;   // partial softmax-denominator for q = qw + li

    for (int k0 = 0; k0 < NSEQ; k0 += 128) {
        // bias for this tile: lane (g,li) needs rows q=li, k = 32kk+8g+(0..7)
        f32x4 bvlo[4], bvhi[4];
        #pragma unroll
        for (int kk = 0; kk < 4; kk++) {
            const float* bp = &bb[(size_t)(qw + li) * NSEQ + k0 + 32 * kk + 8 * g];
            bvlo[kk] = *reinterpret_cast<const f32x4*>(bp);
            bvhi[kk] = *reinterpret_cast<const f32x4*>(bp + 4);
        }

        __syncthreads();
        #pragma unroll
        for (int i = 0; i < 4; i++) {
            *reinterpret_cast<int4*>(&Ks[ksoff[i]]) =
                *reinterpret_cast<const int4*>(&kb[(size_t)k0 * HDIM + ksrc[i]]);
            *reinterpret_cast<int4*>(&Vs[vsoff[i]]) =
                *reinterpret_cast<const int4*>(&vb[(size_t)k0 + vsrc[i]]);
        }
        __syncthreads();

        #pragma unroll
        for (int kk = 0; kk < 4; kk++) {
            // S^T for 32 keys (positions 32kk..32kk+31): 4 MFMA
            f32x4 s0 = f32x4{0.f, 0.f, 0.f, 0.f};
            f32x4 s1 = f32x4{0.f, 0.f, 0.f, 0.f};
            #pragma unroll
            for (int dd = 0; dd < 2; dd++) {
                bf16x8 kf0 = *reinterpret_cast<const bf16x8*>(
                    &Ks[(32 * kk + li) * 72 + 32 * dd + 8 * g]);
                bf16x8 kf1 = *reinterpret_cast<const bf16x8*>(
                    &Ks[(32 * kk + 16 + li) * 72 + 32 * dd + 8 * g]);
                s0 = __builtin_amdgcn_mfma_f32_16x16x32_bf16(kf0, qf[dd], s0, 0, 0, 0);
                s1 = __builtin_amdgcn_mfma_f32_16x16x32_bf16(kf1, qf[dd], s1, 0, 0, 0);
            }
            // p = exp(s + bias); lane holds q=li, k=32kk+8g+(0..7) -> lane-local
            float p0 = __expf(s0[0] + bvlo[kk][0]);
            float p1 = __expf(s0[1] + bvlo[kk][1]);
            float p2 = __expf(s0[2] + bvlo[kk][2]);
            float p3 = __expf(s0[3] + bvlo[kk][3]);
            float p4 = __expf(s1[0] + bvhi[kk][0]);
            float p5 = __expf(s1[1] + bvhi[kk][1]);
            float p6 = __expf(s1[2] + bvhi[kk][2]);
            float p7 = __expf(s1[3] + bvhi[kk][3]);
            lpart += ((p0 + p1) + (p2 + p3)) + ((p4 + p5) + (p6 + p7));
            uint4 pw;
            pw.x = pack_bf16(p0, p1);
            pw.y = pack_bf16(p2, p3);
            pw.z = pack_bf16(p4, p5);
            pw.w = pack_bf16(p6, p7);
            bf16x8 pf = __builtin_bit_cast(bf16x8, pw);
            // PV for this 32-k slab
            #pragma unroll
            for (int dt = 0; dt < 4; dt++) {
                bf16x8 vf = *reinterpret_cast<const bf16x8*>(
                    &Vs[(16 * dt + li) * 136 + 32 * kk + 8 * g]);
                oacc[dt] = __builtin_amdgcn_mfma_f32_16x16x32_bf16(pf, vf, oacc[dt], 0, 0, 0);
            }
        }
    }

    // l-reduce: sum lane partials over g (bits 4,5), gather per output row
    lpart += __shfl_xor(lpart, 16);
    lpart += __shfl_xor(lpart, 32);
    float linv[4];
    #pragma unroll
    for (int r = 0; r < 4; r++)
        linv[r] = 1.f / __shfl(lpart, 4 * g + r);

    #pragma unroll
    for (int dt = 0; dt < 4; dt++)
        #pragma unroll
        for (int r = 0; r < 4; r++) {
            float o = oacc[dt][r] * linv[r];
            int sq = qw + 4 * g + r;
            ybuf[((size_t)b_ * NSEQ + sq) * CDIM + h_ * HDIM + 16 * dt + li] = f2bf(o);
        }
}

// ---------------------------------------------------------------------------
// Proj GEMM: ybuf [4096,768] bf16 @ pwt [768,768] bf16 (pre-transposed)
// + proj_b -> fp32 out.
// ---------------------------------------------------------------------------
__global__ __launch_bounds__(256) void proj_gemm(
    const unsigned short* __restrict__ yb,   // [4096][768]
    const unsigned short* __restrict__ pwt,  // [768][768] (n,k)
    const float* __restrict__ bias, float* __restrict__ out)
{
    __shared__ unsigned short As[128 * 32];
    __shared__ unsigned short Bs[128 * 32];
    const int tid  = threadIdx.x;
    const int lane = tid & 63;
    const int wid  = tid >> 6;
    const int wm = (wid >> 1) * 64, wn = (wid & 1) * 64;
    const int g = lane >> 4, li = lane & 15;
    const int m0 = blockIdx.y * 128;
    const int n0 = blockIdx.x * 128;
    const int srow = lane >> 2;
    const int scol = (lane & 3) * 8;

    f32x4 acc[4][4];
    #pragma unroll
    for (int i = 0; i < 4; i++)
        #pragma unroll
        for (int j = 0; j < 4; j++) acc[i][j] = f32x4{0.f, 0.f, 0.f, 0.f};

    for (int k0 = 0; k0 < CDIM; k0 += 32) {
        __syncthreads();
        #pragma unroll
        for (int c = 0; c < 2; c++) {
            int row = wid * 32 + c * 16 + srow;
            GLOAD_LDS16(&yb[(size_t)(m0 + row) * CDIM + k0 + scol],
                        &As[(wid * 32 + c * 16) * 32]);
            GLOAD_LDS16(&pwt[(size_t)(n0 + row) * CDIM + k0 + scol],
                        &Bs[(wid * 32 + c * 16) * 32]);
        }
        __syncthreads();
        bf16x8 a[4], b[4];
        #pragma unroll
        for (int mt = 0; mt < 4; mt++)
            a[mt] = *reinterpret_cast<const bf16x8*>(&As[(wm + 16 * mt + li) * 32 + 8 * g]);
        #pragma unroll
        for (int nt = 0; nt < 4; nt++)
            b[nt] = *reinterpret_cast<const bf16x8*>(&Bs[(wn + 16 * nt + li) * 32 + 8 * g]);
        #pragma unroll
        for (int mt = 0; mt < 4; mt++)
            #pragma unroll
            for (int nt = 0; nt < 4; nt++)
                acc[mt][nt] = __builtin_amdgcn_mfma_f32_16x16x32_bf16(a[mt], b[nt], acc[mt][nt], 0, 0, 0);
    }

    #pragma unroll
    for (int mt = 0; mt < 4; mt++)
        #pragma unroll
        for (int nt = 0; nt < 4; nt++) {
            int col = n0 + wn + 16 * nt + li;
            float bv = bias[col];
            #pragma unroll
            for (int r = 0; r < 4; r++) {
                int m = m0 + wm + 16 * mt + 4 * g + r;
                out[(size_t)m * CDIM + col] = acc[mt][nt][r] + bv;
            }
        }
}

extern "C" void kernel_launch(void* const* d_in, const int* in_sizes, int n_in,
                              void* d_out, int out_size, void* d_ws, size_t ws_size,
                              hipStream_t stream) {
    const float* x         = (const float*)d_in[0];
    const float* attn_bias = (const float*)d_in[1];
    const float* qkv_w     = (const float*)d_in[2];
    const float* qkv_b     = (const float*)d_in[3];
    const float* proj_w    = (const float*)d_in[4];
    const float* proj_b    = (const float*)d_in[5];
    float* out = (float*)d_out;

    const size_t per = (size_t)BATCH * NHEAD * NSEQ * HDIM;  // 3,145,728
    unsigned short* qbuf  = (unsigned short*)d_ws;
    unsigned short* kbuf  = qbuf + per;
    unsigned short* vtbuf = kbuf + per;
    unsigned short* xb    = vtbuf + per;
    unsigned short* qwt   = xb + per;                    // [2304][768]
    unsigned short* pwt   = qwt + (size_t)QKVN * CDIM;   // [768][768]
    unsigned short* ybuf  = xb;  // x dead after qkv_gemm

    cvt_f32_bf16<<<(MTOT * CDIM / 4 + 255) / 256, 256, 0, stream>>>(
        x, xb, MTOT * CDIM / 4);
    tcvt_f32_bf16<<<dim3(QKVN / 32, CDIM / 32), 256, 0, stream>>>(
        qkv_w, qwt, CDIM, QKVN);
    tcvt_f32_bf16<<<dim3(CDIM / 32, CDIM / 32), 256, 0, stream>>>(
        proj_w, pwt, CDIM, CDIM);

    qkv_gemm<<<dim3(QKVN / 128, MTOT / 128), 256, 0, stream>>>(
        xb, qwt, qkv_b, qbuf, kbuf, vtbuf);
    attn_kernel<<<dim3(NSEQ / 64, BATCH * NHEAD), 256, 0, stream>>>(
        qbuf, kbuf, vtbuf, attn_bias, ybuf);
    proj_gemm<<<dim3(CDIM / 128, MTOT / 128), 256, 0, stream>>>(
        ybuf, pwt, proj_b, out);
}

// Round 10
// 106.833 us; speedup vs baseline: 1.5046x; 1.2136x over previous
//
#include <hip/hip_runtime.h>
#include <hip/hip_bf16.h>

// Problem constants
constexpr int BATCH = 4;
constexpr int NSEQ  = 1024;
constexpr int CDIM  = 768;
constexpr int NHEAD = 12;
constexpr int HDIM  = 64;
constexpr int MTOT  = BATCH * NSEQ;   // 4096
constexpr int QKVN  = 3 * CDIM;       // 2304

typedef __bf16 bf16x8 __attribute__((ext_vector_type(8)));
typedef float  f32x4  __attribute__((ext_vector_type(4)));

__device__ __forceinline__ unsigned short f2bf(float f) {
    unsigned u = __builtin_bit_cast(unsigned, f);
    unsigned r = u + 0x7FFFu + ((u >> 16) & 1u);   // RNE
    return (unsigned short)(r >> 16);
}

#define GLOAD_LDS16(gp, lp)                                                    \
    __builtin_amdgcn_global_load_lds(                                          \
        (const __attribute__((address_space(1))) void*)(gp),                   \
        (__attribute__((address_space(3))) void*)(lp), 16, 0, 0)

// ---------------------------------------------------------------------------
// Prologue converts
// ---------------------------------------------------------------------------
__global__ __launch_bounds__(256) void cvt_f32_bf16(
    const float* __restrict__ in, unsigned short* __restrict__ out, int n4)
{
    int i = blockIdx.x * 256 + threadIdx.x;
    if (i < n4) {
        float4 a = reinterpret_cast<const float4*>(in)[i];
        ushort4 h;
        h.x = f2bf(a.x); h.y = f2bf(a.y); h.z = f2bf(a.z); h.w = f2bf(a.w);
        reinterpret_cast<ushort4*>(out)[i] = h;
    }
}

// in [R][C] f32  ->  out [C][R] bf16  (32x32 tiles)
__global__ __launch_bounds__(256) void tcvt_f32_bf16(
    const float* __restrict__ in, unsigned short* __restrict__ out, int R, int C)
{
    __shared__ unsigned short t[32][33];
    const int c0 = blockIdx.x * 32, r0 = blockIdx.y * 32;
    const int tc = threadIdx.x & 31, tr = threadIdx.x >> 5;  // tr 0..7
    #pragma unroll
    for (int i = 0; i < 4; i++)
        t[tc][tr + 8 * i] = f2bf(in[(size_t)(r0 + tr + 8 * i) * C + c0 + tc]);
    __syncthreads();
    #pragma unroll
    for (int i = 0; i < 4; i++)
        out[(size_t)(c0 + tr + 8 * i) * R + r0 + tc] = t[tr + 8 * i][tc];
}

// ---------------------------------------------------------------------------
// QKV GEMM: xb [4096,768] bf16 @ wt [2304,768] bf16 (pre-transposed) + bias
// -> scatter bf16 into Q*0.125 [B,H,N,64], K [B,H,N,64], Vt [B,H,64,N]
// ---------------------------------------------------------------------------
__global__ __launch_bounds__(256) void qkv_gemm(
    const unsigned short* __restrict__ xb,   // [4096][768]
    const unsigned short* __restrict__ wt,   // [2304][768]
    const float* __restrict__ bias,
    unsigned short* __restrict__ qbuf, unsigned short* __restrict__ kbuf,
    unsigned short* __restrict__ vtbuf)
{
    __shared__ unsigned short As[128 * 32];
    __shared__ unsigned short Bs[128 * 32];
    const int tid  = threadIdx.x;
    const int lane = tid & 63;
    const int wid  = tid >> 6;
    const int wm = (wid >> 1) * 64, wn = (wid & 1) * 64;
    const int g = lane >> 4, li = lane & 15;
    const int m0 = blockIdx.y * 128;
    const int n0 = blockIdx.x * 128;
    const int srow = lane >> 2;
    const int scol = (lane & 3) * 8;

    f32x4 acc[4][4];
    #pragma unroll
    for (int i = 0; i < 4; i++)
        #pragma unroll
        for (int j = 0; j < 4; j++) acc[i][j] = f32x4{0.f, 0.f, 0.f, 0.f};

    for (int k0 = 0; k0 < CDIM; k0 += 32) {
        __syncthreads();
        #pragma unroll
        for (int c = 0; c < 2; c++) {
            int row = wid * 32 + c * 16 + srow;
            GLOAD_LDS16(&xb[(size_t)(m0 + row) * CDIM + k0 + scol],
                        &As[(wid * 32 + c * 16) * 32]);
            GLOAD_LDS16(&wt[(size_t)(n0 + row) * CDIM + k0 + scol],
                        &Bs[(wid * 32 + c * 16) * 32]);
        }
        __syncthreads();
        bf16x8 a[4], b[4];
        #pragma unroll
        for (int mt = 0; mt < 4; mt++)
            a[mt] = *reinterpret_cast<const bf16x8*>(&As[(wm + 16 * mt + li) * 32 + 8 * g]);
        #pragma unroll
        for (int nt = 0; nt < 4; nt++)
            b[nt] = *reinterpret_cast<const bf16x8*>(&Bs[(wn + 16 * nt + li) * 32 + 8 * g]);
        #pragma unroll
        for (int mt = 0; mt < 4; mt++)
            #pragma unroll
            for (int nt = 0; nt < 4; nt++)
                acc[mt][nt] = __builtin_amdgcn_mfma_f32_16x16x32_bf16(a[mt], b[nt], acc[mt][nt], 0, 0, 0);
    }

    #pragma unroll
    for (int mt = 0; mt < 4; mt++) {
        #pragma unroll
        for (int nt = 0; nt < 4; nt++) {
            int col  = n0 + wn + 16 * nt + li;
            int tsel = col / CDIM;
            int rem  = col - tsel * CDIM;
            int h_ = rem >> 6, d = rem & 63;
            float bv = bias[col];
            float sc = (tsel == 0) ? 0.125f : 1.0f;
            #pragma unroll
            for (int r = 0; r < 4; r++) {
                int m  = m0 + wm + 16 * mt + 4 * g + r;
                int b_ = m >> 10, s = m & 1023;
                unsigned short hv = f2bf((acc[mt][nt][r] + bv) * sc);
                if (tsel == 0)
                    qbuf[(((size_t)b_ * NHEAD + h_) * NSEQ + s) * HDIM + d] = hv;
                else if (tsel == 1)
                    kbuf[(((size_t)b_ * NHEAD + h_) * NSEQ + s) * HDIM + d] = hv;
                else
                    vtbuf[(((size_t)b_ * NHEAD + h_) * HDIM + d) * NSEQ + s] = hv;
            }
        }
    }
}

// ---------------------------------------------------------------------------
// Flash-style attention, no-max softmax (|logit| <= ~8 for this problem).
// r3 compute body (best measured) + r7's async double-buffered K/V staging
// via global_load_lds (zero-VGPR prefetch; r7 validated the swizzle math).
// Linear LDS tiles with rule-#21 source-XOR swizzle (slot ^= row&7) so the
// column-slice ds_read_b128 is bank-spread. Bias loaded fresh within each
// phase (NO cross-barrier register state -> no scratch spill; r4/r5/r7
// lesson). KVBLK=64, 16 tiles, 2 phases/iter. LDS 41.9KB -> 3 blocks/CU.
// ---------------------------------------------------------------------------
__global__ __launch_bounds__(256, 3) void attn_kernel(
    const unsigned short* __restrict__ qbuf,
    const unsigned short* __restrict__ kbuf,
    const unsigned short* __restrict__ vtbuf,
    const float* __restrict__ bias,     // [H,N,N]
    unsigned short* __restrict__ ybuf)  // [B,N,C] bf16
{
    __shared__ unsigned short Kl[2][64 * 64];  // [k][d] linear, source-swizzled
    __shared__ unsigned short Vl[2][64 * 64];  // V^T [d][k] linear, swizzled
    __shared__ unsigned short Ps[4][16][72];   // per-wave P: [q][k]

    const int tid  = threadIdx.x;
    const int lane = tid & 63;
    const int wid  = tid >> 6;
    const int g = lane >> 4, li = lane & 15;
    const int srow8 = lane >> 3;               // 0..7
    const int scs   = (lane & 7) ^ srow8;      // swizzled source slot (16B units)
    const int bh = blockIdx.y;
    const int b_ = bh / NHEAD, h_ = bh % NHEAD;
    const int qw = blockIdx.x * 64 + wid * 16;

    const unsigned short* qb = qbuf + (size_t)bh * NSEQ * HDIM;
    const unsigned short* kb = kbuf + (size_t)bh * NSEQ * HDIM;
    const unsigned short* vb = vtbuf + (size_t)bh * HDIM * NSEQ;
    const float* bb = bias + (size_t)h_ * NSEQ * NSEQ;

    // async stage of 64-key tile T into (KL,VL): 2+2 global_load_lds per wave.
    // LDS dest linear; global source slot XOR'd with row&7 (both-sides rule).
#define STAGE_KV(T, KL, VL)                                                    \
    {                                                                          \
        _Pragma("unroll") for (int i = 0; i < 2; i++) {                        \
            GLOAD_LDS16(kb + (size_t)((T) * 64 + wid * 16 + i * 8 + srow8) * HDIM + scs * 8, \
                        (KL) + (wid * 16 + i * 8) * 64);                       \
            GLOAD_LDS16(vb + (size_t)(wid * 16 + i * 8 + srow8) * NSEQ + (T) * 64 + scs * 8, \
                        (VL) + (wid * 16 + i * 8) * 64);                       \
        }                                                                      \
    }

    // r3 compute body on one 64-key tile (KS/VS = current buffers, T = tile)
#define COMPUTE_TILE(KS, VS, T)                                                \
    {                                                                          \
        float bv[4][4];                                                        \
        _Pragma("unroll") for (int kt = 0; kt < 4; kt++)                       \
            _Pragma("unroll") for (int r = 0; r < 4; r++)                      \
                bv[kt][r] = bb[(size_t)(qw + 4 * g + r) * NSEQ + (T) * 64 + 16 * kt + li]; \
        f32x4 sacc[4];                                                         \
        _Pragma("unroll") for (int kt = 0; kt < 4; kt++)                       \
            sacc[kt] = f32x4{0.f, 0.f, 0.f, 0.f};                              \
        _Pragma("unroll") for (int kt = 0; kt < 4; kt++)                       \
            _Pragma("unroll") for (int dd = 0; dd < 2; dd++) {                 \
                bf16x8 kf = *reinterpret_cast<const bf16x8*>(                  \
                    (KS) + (16 * kt + li) * 64 + (((4 * dd + g) ^ (li & 7)) * 8)); \
                sacc[kt] = __builtin_amdgcn_mfma_f32_16x16x32_bf16(qf[dd], kf, sacc[kt], 0, 0, 0); \
            }                                                                  \
        _Pragma("unroll") for (int kt = 0; kt < 4; kt++)                       \
            _Pragma("unroll") for (int r = 0; r < 4; r++) {                    \
                float pv = __expf(sacc[kt][r] + bv[kt][r]);                    \
                lpart[r] += pv;                                                \
                Ps[wid][4 * g + r][16 * kt + li] = f2bf(pv);                   \
            }                                                                  \
        _Pragma("unroll") for (int kk = 0; kk < 2; kk++) {                     \
            bf16x8 pf = *reinterpret_cast<const bf16x8*>(&Ps[wid][li][32 * kk + 8 * g]); \
            _Pragma("unroll") for (int dt = 0; dt < 4; dt++) {                 \
                bf16x8 vf = *reinterpret_cast<const bf16x8*>(                  \
                    (VS) + (16 * dt + li) * 64 + (((4 * kk + g) ^ (li & 7)) * 8)); \
                oacc[dt] = __builtin_amdgcn_mfma_f32_16x16x32_bf16(pf, vf, oacc[dt], 0, 0, 0); \
            }                                                                  \
        }                                                                      \
    }

    bf16x8 qf[2];
    #pragma unroll
    for (int dd = 0; dd < 2; dd++)
        qf[dd] = *reinterpret_cast<const bf16x8*>(&qb[(size_t)(qw + li) * HDIM + 32 * dd + 8 * g]);

    f32x4 oacc[4];
    #pragma unroll
    for (int dt = 0; dt < 4; dt++) oacc[dt] = f32x4{0.f, 0.f, 0.f, 0.f};
    float lpart[4] = {0.f, 0.f, 0.f, 0.f};

    // prologue: stage tile 0 into buf0; barrier drains the DMA
    STAGE_KV(0, Kl[0], Vl[0]);
    __syncthreads();

    for (int j = 0; j < 8; ++j) {
        const int tA = 2 * j;
        // phase A: stage tile tA+1 -> buf1 (async), compute tile tA from buf0
        STAGE_KV(tA + 1, Kl[1], Vl[1]);
        COMPUTE_TILE(Kl[0], Vl[0], tA);
        __syncthreads();   // waves done with buf0; tA+1 DMA drained

        // phase B: stage tile tA+2 -> buf0 (async), compute tile tA+1 from buf1
        if (j < 7) STAGE_KV(tA + 2, Kl[0], Vl[0]);
        COMPUTE_TILE(Kl[1], Vl[1], tA + 1);
        __syncthreads();   // waves done with buf1; tA+2 DMA drained
    }

    // l-reduce over li group + epilogue
    float linv[4];
    #pragma unroll
    for (int r = 0; r < 4; r++) {
        float s = lpart[r];
        s += __shfl_xor(s, 1);
        s += __shfl_xor(s, 2);
        s += __shfl_xor(s, 4);
        s += __shfl_xor(s, 8);
        linv[r] = 1.f / s;
    }
    #pragma unroll
    for (int dt = 0; dt < 4; dt++)
        #pragma unroll
        for (int r = 0; r < 4; r++) {
            float o = oacc[dt][r] * linv[r];
            int sq = qw + 4 * g + r;
            ybuf[((size_t)b_ * NSEQ + sq) * CDIM + h_ * HDIM + 16 * dt + li] = f2bf(o);
        }
#undef STAGE_KV
#undef COMPUTE_TILE
}

// ---------------------------------------------------------------------------
// Proj GEMM: ybuf [4096,768] bf16 @ pwt [768,768] bf16 (pre-transposed)
// + proj_b -> fp32 out.
// ---------------------------------------------------------------------------
__global__ __launch_bounds__(256) void proj_gemm(
    const unsigned short* __restrict__ yb,   // [4096][768]
    const unsigned short* __restrict__ pwt,  // [768][768] (n,k)
    const float* __restrict__ bias, float* __restrict__ out)
{
    __shared__ unsigned short As[128 * 32];
    __shared__ unsigned short Bs[128 * 32];
    const int tid  = threadIdx.x;
    const int lane = tid & 63;
    const int wid  = tid >> 6;
    const int wm = (wid >> 1) * 64, wn = (wid & 1) * 64;
    const int g = lane >> 4, li = lane & 15;
    const int m0 = blockIdx.y * 128;
    const int n0 = blockIdx.x * 128;
    const int srow = lane >> 2;
    const int scol = (lane & 3) * 8;

    f32x4 acc[4][4];
    #pragma unroll
    for (int i = 0; i < 4; i++)
        #pragma unroll
        for (int j = 0; j < 4; j++) acc[i][j] = f32x4{0.f, 0.f, 0.f, 0.f};

    for (int k0 = 0; k0 < CDIM; k0 += 32) {
        __syncthreads();
        #pragma unroll
        for (int c = 0; c < 2; c++) {
            int row = wid * 32 + c * 16 + srow;
            GLOAD_LDS16(&yb[(size_t)(m0 + row) * CDIM + k0 + scol],
                        &As[(wid * 32 + c * 16) * 32]);
            GLOAD_LDS16(&pwt[(size_t)(n0 + row) * CDIM + k0 + scol],
                        &Bs[(wid * 32 + c * 16) * 32]);
        }
        __syncthreads();
        bf16x8 a[4], b[4];
        #pragma unroll
        for (int mt = 0; mt < 4; mt++)
            a[mt] = *reinterpret_cast<const bf16x8*>(&As[(wm + 16 * mt + li) * 32 + 8 * g]);
        #pragma unroll
        for (int nt = 0; nt < 4; nt++)
            b[nt] = *reinterpret_cast<const bf16x8*>(&Bs[(wn + 16 * nt + li) * 32 + 8 * g]);
        #pragma unroll
        for (int mt = 0; mt < 4; mt++)
            #pragma unroll
            for (int nt = 0; nt < 4; nt++)
                acc[mt][nt] = __builtin_amdgcn_mfma_f32_16x16x32_bf16(a[mt], b[nt], acc[mt][nt], 0, 0, 0);
    }

    #pragma unroll
    for (int mt = 0; mt < 4; mt++)
        #pragma unroll
        for (int nt = 0; nt < 4; nt++) {
            int col = n0 + wn + 16 * nt + li;
            float bv = bias[col];
            #pragma unroll
            for (int r = 0; r < 4; r++) {
                int m = m0 + wm + 16 * mt + 4 * g + r;
                out[(size_t)m * CDIM + col] = acc[mt][nt][r] + bv;
            }
        }
}

extern "C" void kernel_launch(void* const* d_in, const int* in_sizes, int n_in,
                              void* d_out, int out_size, void* d_ws, size_t ws_size,
                              hipStream_t stream) {
    const float* x         = (const float*)d_in[0];
    const float* attn_bias = (const float*)d_in[1];
    const float* qkv_w     = (const float*)d_in[2];
    const float* qkv_b     = (const float*)d_in[3];
    const float* proj_w    = (const float*)d_in[4];
    const float* proj_b    = (const float*)d_in[5];
    float* out = (float*)d_out;

    const size_t per = (size_t)BATCH * NHEAD * NSEQ * HDIM;  // 3,145,728
    unsigned short* qbuf  = (unsigned short*)d_ws;
    unsigned short* kbuf  = qbuf + per;
    unsigned short* vtbuf = kbuf + per;
    unsigned short* xb    = vtbuf + per;
    unsigned short* qwt   = xb + per;                    // [2304][768]
    unsigned short* pwt   = qwt + (size_t)QKVN * CDIM;   // [768][768]
    unsigned short* ybuf  = xb;  // x dead after qkv_gemm

    cvt_f32_bf16<<<(MTOT * CDIM / 4 + 255) / 256, 256, 0, stream>>>(
        x, xb, MTOT * CDIM / 4);
    tcvt_f32_bf16<<<dim3(QKVN / 32, CDIM / 32), 256, 0, stream>>>(
        qkv_w, qwt, CDIM, QKVN);
    tcvt_f32_bf16<<<dim3(CDIM / 32, CDIM / 32), 256, 0, stream>>>(
        proj_w, pwt, CDIM, CDIM);

    qkv_gemm<<<dim3(QKVN / 128, MTOT / 128), 256, 0, stream>>>(
        xb, qwt, qkv_b, qbuf, kbuf, vtbuf);
    attn_kernel<<<dim3(NSEQ / 64, BATCH * NHEAD), 256, 0, stream>>>(
        qbuf, kbuf, vtbuf, attn_bias, ybuf);
    proj_gemm<<<dim3(CDIM / 128, MTOT / 128), 256, 0, stream>>>(
        ybuf, pwt, proj_b, out);
}